// Round 9
// baseline (63.708 us; speedup 1.0000x reference)
//
#include <hip/hip_runtime.h>
#include <math.h>

#define M_WAVE 32
#define NLEN 8192
#define FFT_N 16384
#define THREADS 1024
#define NPAIR 528   // 496 cross (blocks 0..495) + 32 autos (blocks 496..527)

#define TWOPI_F 6.28318530717958647692f

__device__ __forceinline__ float2 cadd(float2 a, float2 b){return make_float2(a.x+b.x, a.y+b.y);}
__device__ __forceinline__ float2 csub(float2 a, float2 b){return make_float2(a.x-b.x, a.y-b.y);}
__device__ __forceinline__ float2 cmul(float2 a, float2 b){return make_float2(a.x*b.x-a.y*b.y, a.x*b.y+a.y*b.x);}
__device__ __forceinline__ float2 mul_i (float2 a){return make_float2(-a.y,  a.x);}
__device__ __forceinline__ float2 mul_mi(float2 a){return make_float2( a.y, -a.x);}

// bf16x2 pack/unpack: one complex float2 <-> one u32 (re=low16, im=high16)
__device__ __forceinline__ unsigned pkc(float2 v){
    unsigned r;
    asm("v_cvt_pk_bf16_f32 %0, %1, %2" : "=v"(r) : "v"(v.x), "v"(v.y));
    return r;
}
__device__ __forceinline__ float2 upkc(unsigned u){
    return make_float2(__uint_as_float(u << 16), __uint_as_float(u & 0xFFFF0000u));
}

__device__ __forceinline__ float2 dpp_xor1(float2 v){
    float2 r;
    r.x = __int_as_float(__builtin_amdgcn_mov_dpp(__float_as_int(v.x), 0xB1, 0xF, 0xF, true));
    r.y = __int_as_float(__builtin_amdgcn_mov_dpp(__float_as_int(v.y), 0xB1, 0xF, 0xF, true));
    return r;
}
__device__ __forceinline__ float2 dpp_xor2(float2 v){
    float2 r;
    r.x = __int_as_float(__builtin_amdgcn_mov_dpp(__float_as_int(v.x), 0x4E, 0xF, 0xF, true));
    r.y = __int_as_float(__builtin_amdgcn_mov_dpp(__float_as_int(v.y), 0x4E, 0xF, 0xF, true));
    return r;
}

__device__ __forceinline__ float waveReduceMax(float v) {
    #pragma unroll
    for (int off = 32; off > 0; off >>= 1) v = fmaxf(v, __shfl_down(v, off, 64));
    return v;
}
__device__ __forceinline__ float waveReduceSum(float v) {
    #pragma unroll
    for (int off = 32; off > 0; off >>= 1) v += __shfl_down(v, off, 64);
    return v;
}

// ---------- classic dft16 (natural order) -- used by fwd kernel only ----------
template<int SGN>
__device__ __forceinline__ void dft16_tail(float2 w[16], float2 v[16]){
    const float C1 = 0.923879532511286756f;
    const float S1 = 0.382683432365089772f;
    const float R2 = 0.707106781186547524f;
    const float G = (SGN < 0) ? -1.0f : 1.0f;
    w[5]  = cmul(w[5],  make_float2( C1,  G*S1));
    w[6]  = cmul(w[6],  make_float2( R2,  G*R2));
    w[7]  = cmul(w[7],  make_float2( S1,  G*C1));
    w[9]  = cmul(w[9],  make_float2( R2,  G*R2));
    w[10] = (SGN<0) ? mul_mi(w[10]) : mul_i(w[10]);
    w[11] = cmul(w[11], make_float2(-R2,  G*R2));
    w[13] = cmul(w[13], make_float2( S1,  G*C1));
    w[14] = cmul(w[14], make_float2(-R2,  G*R2));
    w[15] = cmul(w[15], make_float2(-C1, -G*S1));
    #pragma unroll
    for (int k0 = 0; k0 < 4; ++k0){
        float2 a = w[k0*4+0], b = w[k0*4+1], c = w[k0*4+2], d = w[k0*4+3];
        float2 t0 = cadd(a,c), t1 = csub(a,c), t2 = cadd(b,d), t3 = csub(b,d);
        float2 j3 = (SGN < 0) ? mul_mi(t3) : mul_i(t3);
        v[k0]    = cadd(t0,t2);
        v[k0+4]  = cadd(t1,j3);
        v[k0+8]  = csub(t0,t2);
        v[k0+12] = csub(t1,j3);
    }
}

template<int SGN>
__device__ __forceinline__ void dft16(float2 v[16]){
    float2 w[16];
    #pragma unroll
    for (int n0 = 0; n0 < 4; ++n0){
        float2 a = v[n0], b = v[n0+4], c = v[n0+8], d = v[n0+12];
        float2 t0 = cadd(a,c), t1 = csub(a,c), t2 = cadd(b,d), t3 = csub(b,d);
        float2 j3 = (SGN < 0) ? mul_mi(t3) : mul_i(t3);
        w[n0]    = cadd(t0,t2);
        w[4+n0]  = cadd(t1,j3);
        w[8+n0]  = csub(t0,t2);
        w[12+n0] = csub(t1,j3);
    }
    dft16_tail<SGN>(w, v);
}

// forward DFT16 with inputs 8..15 == 0 (zero-padded), SGN=-1
__device__ __forceinline__ void dft16_zero8(float2 v[16]){
    float2 w[16];
    #pragma unroll
    for (int n0 = 0; n0 < 4; ++n0){
        float2 a = v[n0], b = v[n0+4];
        w[n0]    = cadd(a,b);
        w[4+n0]  = make_float2(a.x + b.y, a.y - b.x);  // a - i b
        w[8+n0]  = csub(a,b);
        w[12+n0] = make_float2(a.x - b.y, a.y + b.x);  // a + i b
    }
    dft16_tail<-1>(w, v);
}

// ---------- in-place dft16, digit-reversed output: slot s holds y[4*(s&3)+(s>>2)].
// Peak live state ~v[16]+temps (vs w[16]+v[16] for the classic one). Pair kernel only.
template<int SGN>
__device__ __forceinline__ void dft16_ip(float2 v[16]){
    const float C1 = 0.923879532511286756f;
    const float S1 = 0.382683432365089772f;
    const float R2 = 0.707106781186547524f;
    const float G = (SGN < 0) ? -1.0f : 1.0f;
    // pass 1: DFT4 over n2 within {n1, n1+4, n1+8, n1+12}, in place; slot n1+4*k_lo = z[n1,k_lo]
    #pragma unroll
    for (int n1 = 0; n1 < 4; ++n1){
        float2 a = v[n1], b = v[n1+4], c = v[n1+8], d = v[n1+12];
        float2 t0 = cadd(a,c), t1 = csub(a,c), t2 = cadd(b,d), t3 = csub(b,d);
        float2 j3 = (SGN < 0) ? mul_mi(t3) : mul_i(t3);
        v[n1]    = cadd(t0,t2);
        v[n1+4]  = cadd(t1,j3);
        v[n1+8]  = csub(t0,t2);
        v[n1+12] = csub(t1,j3);
    }
    // twiddle W16^{SGN*n1*k_lo} on slot n1+4*k_lo
    v[5]  = cmul(v[5],  make_float2( C1,  G*S1));   // m=1
    v[6]  = cmul(v[6],  make_float2( R2,  G*R2));   // m=2
    v[7]  = cmul(v[7],  make_float2( S1,  G*C1));   // m=3
    v[9]  = cmul(v[9],  make_float2( R2,  G*R2));   // m=2
    v[10] = (SGN<0) ? mul_mi(v[10]) : mul_i(v[10]); // m=4
    v[11] = cmul(v[11], make_float2(-R2,  G*R2));   // m=6
    v[13] = cmul(v[13], make_float2( S1,  G*C1));   // m=3
    v[14] = cmul(v[14], make_float2(-R2,  G*R2));   // m=6
    v[15] = cmul(v[15], make_float2(-C1, -G*S1));   // m=9
    // pass 2: DFT4 over n1 within {4k_lo..4k_lo+3}; slot 4k_lo+k_hi = y[k_lo+4k_hi]
    #pragma unroll
    for (int kl = 0; kl < 4; ++kl){
        float2 a = v[4*kl], b = v[4*kl+1], c = v[4*kl+2], d = v[4*kl+3];
        float2 t0 = cadd(a,c), t1 = csub(a,c), t2 = cadd(b,d), t3 = csub(b,d);
        float2 j3 = (SGN < 0) ? mul_mi(t3) : mul_i(t3);
        v[4*kl]   = cadd(t0,t2);
        v[4*kl+1] = cadd(t1,j3);
        v[4*kl+2] = csub(t0,t2);
        v[4*kl+3] = csub(t1,j3);
    }
}

template<int SGN>
__device__ __forceinline__ void twchain16(float2 v[16], float theta){
    float th = (SGN < 0) ? -theta : theta;
    float s1,c1; __sincosf(th, &s1, &c1);
    float s4,c4; __sincosf(4.0f*th, &s4, &c4);
    float2 w1 = make_float2(c1,s1), w4 = make_float2(c4,s4);
    float2 lo2 = cmul(w1,w1), lo3 = cmul(lo2,w1);
    float2 hi2 = cmul(w4,w4), hi3 = cmul(hi2,w4);
    float2 lo[4] = {make_float2(1.f,0.f), w1, lo2, lo3};
    float2 hi[4] = {make_float2(1.f,0.f), w4, hi2, hi3};
    #pragma unroll
    for (int s = 1; s < 16; ++s){
        v[s] = cmul(v[s], cmul(hi[s>>2], lo[s&3]));
    }
}

__device__ __forceinline__ int L1swz(int e){
    return (e & ~63) | (((e & 63) + ((e >> 6) & 15)) & 63);
}

// Forward FFT: 128 blocks = 32 m x 4 quarters, 256 threads (R4-verified body),
// bf16x2 store in the same spec layout the pair kernel reads (v[k] at offset k).
__global__ __launch_bounds__(256, 1) void fwd_fft_kernel(const float* __restrict__ x,
                                                         unsigned* __restrict__ spec) {
    __shared__ float2 X4[4096];  // 32 KiB
    const int bx = blockIdx.x, m = bx >> 2, qt = bx & 3;
    const int tid = threadIdx.x;

    // Stage A: 4 columns per thread; keep outputs s = 4qt..4qt+3
    #pragma unroll 1
    for (int cc = 0; cc < 4; ++cc){
        const int j = cc*256 + tid;
        float2 v[16];
        #pragma unroll
        for (int s = 0; s < 8; ++s){
            float ph = TWOPI_F * x[m*NLEN + s*1024 + j];
            float sn,cs; __sincosf(ph,&sn,&cs);
            v[s] = make_float2(cs,sn);
        }
        dft16_zero8(v);
        const float th = TWOPI_F * (float)j / 16384.0f;
        float sb,cb; __sincosf(-(float)(4*qt)*th, &sb, &cb);
        float ss,cs2; __sincosf(-th, &ss, &cs2);
        float2 wcur = make_float2(cb,sb), wstep = make_float2(cs2,ss);
        #pragma unroll
        for (int d = 0; d < 4; ++d){
            X4[d*1024 + L1swz(j)] = cmul(v[4*qt + d], wcur);
            wcur = cmul(wcur, wstep);
        }
    }
    __syncthreads();

    // Stage B: wave w = local chunk w (global chunk 4qt+w)
    const int wv = tid >> 6, jB = tid & 63;
    float2 v[16];
    #pragma unroll
    for (int t = 0; t < 16; ++t) v[t] = X4[wv*1024 + t*64 + ((jB + t) & 63)];
    dft16<-1>(v);
    twchain16<-1>(v, TWOPI_F * (float)jB / 1024.0f);
    #pragma unroll
    for (int sp = 0; sp < 16; ++sp) X4[wv*1024 + sp*64 + ((jB + 4*sp) & 63)] = v[sp];
    // no barrier: stage C reads only this wave's chunk

    // Stage C: DFT16 + tw W64 + 4-lane DPP DFT4, bf16 store
    {
        const int bl = (tid & 63) >> 2, jC = tid & 3;
        #pragma unroll
        for (int a = 0; a < 16; ++a)
            v[a] = X4[wv*1024 + bl*64 + ((4*a + jC + 4*bl) & 63)];
        dft16<-1>(v);
        twchain16<-1>(v, TWOPI_F * (float)jC / 64.0f);
        const bool odd1 = (jC & 1) != 0;
        const bool odd2 = (jC & 2) != 0;
        #pragma unroll
        for (int e = 0; e < 16; ++e){
            float2 p = dpp_xor2(v[e]);
            float2 t = odd2 ? csub(p, v[e]) : cadd(v[e], p);
            float2 q = dpp_xor1(t);
            float2 re = odd1 ? csub(q, t) : cadd(t, q);
            float2 ro = odd1 ? cadd(q, mul_i(t)) : cadd(t, mul_mi(q));
            v[e] = odd2 ? ro : re;
        }
        const int u = ((jC & 1) << 1) | (jC >> 1);
        uint4* dst = (uint4*)(spec + (size_t)m*FFT_N + (4*qt + wv)*1024 + bl*64 + u*16);
        #pragma unroll
        for (int e = 0; e < 4; ++e)
            dst[e] = make_uint4(pkc(v[4*e]), pkc(v[4*e+1]), pkc(v[4*e+2]), pkc(v[4*e+3]));
    }
}

// Pair kernel: bf16 LDS (64 KiB -> 2 blocks/CU), in-place dft16 (digit-reversed
// output compensated statically in store maps and stats), no uval array.
__global__ __launch_bounds__(THREADS, 8) void pair_kernel(const unsigned* __restrict__ spec,
                                                          float4* __restrict__ rec) {
    __shared__ unsigned X[FFT_N];  // 64 KiB, bf16x2 per element
    const int r = blockIdx.x, tid = threadIdx.x;
    const bool is_auto = (r >= 496);
    int a, b, rec_idx;
    if (is_auto){
        a = b = r - 496;
        rec_idx = r - 496;           // autos -> rec[0..31]
    } else {
        int t = r; a = 0; int rem = M_WAVE - 1;
        while (t >= rem){ t -= rem; ++a; rem = M_WAVE - 1 - a; }
        b = a + 1 + t;
        rec_idx = M_WAVE + r;        // cross -> rec[32..527]
    }
    const int blk = tid >> 2, jC = tid & 3;
    const int u = ((jC & 1) << 1) | (jC >> 1);
    float2 v[16];

    // Load both spectra (bf16x2, 64 B contiguous each), product B*conj(A)
    {
        const uint4* pa = (const uint4*)(spec + (size_t)a*FFT_N + blk*64 + u*16);
        const uint4* pb = (const uint4*)(spec + (size_t)b*FFT_N + blk*64 + u*16);
        #pragma unroll
        for (int e = 0; e < 4; ++e){
            uint4 A = pa[e], B = pb[e];
            float2 a0 = upkc(A.x), a1 = upkc(A.y), a2 = upkc(A.z), a3 = upkc(A.w);
            float2 b0 = upkc(B.x), b1 = upkc(B.y), b2 = upkc(B.z), b3 = upkc(B.w);
            v[4*e+0] = make_float2(b0.x*a0.x + b0.y*a0.y, b0.y*a0.x - b0.x*a0.y);
            v[4*e+1] = make_float2(b1.x*a1.x + b1.y*a1.y, b1.y*a1.x - b1.x*a1.y);
            v[4*e+2] = make_float2(b2.x*a2.x + b2.y*a2.y, b2.y*a2.x - b2.x*a2.y);
            v[4*e+3] = make_float2(b3.x*a3.x + b3.y*a3.y, b3.y*a3.x - b3.x*a3.y);
        }
    }
    // Stage C': adjoint lane-DFT4, conj twiddle W64, dft16_ip, LDS write (rev map)
    {
        const bool odd1 = (jC & 1) != 0;
        const bool odd2 = (jC & 2) != 0;
        #pragma unroll
        for (int e = 0; e < 16; ++e){
            float2 q = dpp_xor1(v[e]);
            float2 t = odd1 ? csub(q, v[e]) : cadd(v[e], q);
            float2 p = dpp_xor2(t);
            float2 re = odd2 ? csub(p, t) : cadd(t, p);
            float2 ro = odd2 ? csub(p, mul_i(t)) : cadd(t, mul_i(p));
            v[e] = odd1 ? ro : re;
        }
        twchain16<+1>(v, TWOPI_F * (float)jC / 64.0f);
        dft16_ip<+1>(v);
        const int rot = 4*(blk & 15);
        #pragma unroll
        for (int s = 0; s < 16; ++s){
            const int t = 4*(s&3) + (s>>2);   // digit held in slot s
            X[blk*64 + ((4*t + jC + rot) & 63)] = pkc(v[s]);
        }
    }
    // no barrier: B' reads only this wave's chunk
    // Stage B'
    {
        const int sB = tid >> 6, jB = tid & 63;
        #pragma unroll
        for (int sp = 0; sp < 16; ++sp) v[sp] = upkc(X[sB*1024 + sp*64 + ((jB + 4*sp) & 63)]);
        twchain16<+1>(v, TWOPI_F * (float)jB / 1024.0f);
        dft16_ip<+1>(v);
        #pragma unroll
        for (int s = 0; s < 16; ++s){
            const int t = 4*(s&3) + (s>>2);
            X[sB*1024 + t*64 + ((jB + t) & 63)] = pkc(v[s]);
        }
    }
    __syncthreads();   // cross-wave: A' gathers from all chunks
    // Stage A': slot s holds 16384*sigma[rev(s)*1024 + tid]
    {
        const int baseA = L1swz(tid);
        #pragma unroll
        for (int s = 0; s < 16; ++s) v[s] = upkc(X[s*1024 + baseA]);
        twchain16<+1>(v, TWOPI_F * (float)tid / 16384.0f);
        dft16_ip<+1>(v);
    }

    // Stats. digit t = rev(s). Auto: n in [N+1,2N-1]; cross: all except N, n=0 double.
    const float CSCALE = 0.1f / (16384.0f * 16384.0f);
    const bool j0 = (tid == 0);
    float lm = 0.f, lsum = 0.f;
    #pragma unroll
    for (int s = 0; s < 16; ++s){
        const int t = 4*(s&3) + (s>>2);
        float uu = CSCALE * (v[s].x*v[s].x + v[s].y*v[s].y);
        if (is_auto){
            bool valid = (t > 8) || ((t == 8) && !j0);
            if (valid){ lm = fmaxf(lm, uu); lsum += uu; }
        } else {
            bool inv = (t == 8) && j0;
            if (!inv){ lm = fmaxf(lm, uu); lsum += uu; }
            if (t == 0 && j0) lsum += uu;
        }
    }
    __syncthreads();  // X reads done; reuse as scratch

    float* scratch = (float*)X;
    const int lane = tid & 63, wvv = tid >> 6;
    float wm = waveReduceMax(lm);
    float wsm = waveReduceSum(lsum);
    if (lane == 0){ scratch[wvv] = wm; scratch[16+wvv] = wsm; }
    __syncthreads();
    float m_b = scratch[0], sumu = scratch[16];
    #pragma unroll
    for (int i = 1; i < 16; ++i){ m_b = fmaxf(m_b, scratch[i]); sumu += scratch[16+i]; }

    const float invTN2 = 1.0f / 67108.864f;   // 1/(T*N*N)
    float le = 0.f;
    #pragma unroll
    for (int s = 0; s < 16; ++s){
        const int t = 4*(s&3) + (s>>2);
        float uu = CSCALE * (v[s].x*v[s].x + v[s].y*v[s].y);
        float ex = __expf((uu - m_b) * invTN2);
        if (is_auto){
            bool valid = (t > 8) || ((t == 8) && !j0);
            if (valid) le += ex;
        } else {
            bool inv = (t == 8) && j0;
            if (!inv) le += ((t == 0 && j0) ? 2.f : 1.f) * ex;
        }
    }
    float wle = waveReduceSum(le);
    if (lane == 0) scratch[32+wvv] = wle;
    __syncthreads();
    if (tid == 0){
        float sb2 = 0.f;
        #pragma unroll
        for (int i = 0; i < 16; ++i) sb2 += scratch[32+i];
        rec[rec_idx] = make_float4(m_b, sumu, sb2, 0.f);
    }
}

// Merge 528 records -> 7 outputs. Single wave, shuffle-only, deterministic.
__global__ __launch_bounds__(64) void final_kernel(const float4* __restrict__ rec,
                                                   float* __restrict__ out) {
    const int lane = threadIdx.x;
    float mA = 0.f, mC = 0.f;
    for (int r = lane; r < NPAIR; r += 64){
        float mx = rec[r].x;
        if (r < M_WAVE) mA = fmaxf(mA, mx); else mC = fmaxf(mC, mx);
    }
    #pragma unroll
    for (int off = 32; off > 0; off >>= 1){
        mA = fmaxf(mA, __shfl_xor(mA, off, 64));
        mC = fmaxf(mC, __shfl_xor(mC, off, 64));
    }
    const float Mall = fmaxf(mA, mC);
    const float invTN2f = 1.0f / 67108.864f;
    double S = 0.0, sA = 0.0, sC = 0.0;
    for (int r = lane; r < NPAIR; r += 64){
        float4 rv = rec[r];
        S += (double)rv.z * (double)__expf((rv.x - Mall)*invTN2f);
        if (r < M_WAVE) sA += (double)rv.y; else sC += (double)rv.y;
    }
    #pragma unroll
    for (int off = 32; off > 0; off >>= 1){
        S  += __shfl_xor(S,  off, 64);
        sA += __shfl_xor(sA, off, 64);
        sC += __shfl_xor(sC, off, 64);
    }
    if (lane == 0){
        const double invN2 = 1.0/67108864.0;
        out[0] = (float)((double)Mall*invN2 + 1e-3*log(S));
        out[1] = (float)((double)Mall*invN2);
        out[2] = mA;
        out[3] = mC;
        out[4] = (float)((sA + sC)*invN2);
        out[5] = (float)sA;
        out[6] = (float)sC;
    }
}

extern "C" void kernel_launch(void* const* d_in, const int* in_sizes, int n_in,
                              void* d_out, int out_size, void* d_ws, size_t ws_size,
                              hipStream_t stream) {
    (void)in_sizes; (void)n_in; (void)out_size; (void)ws_size;
    const float* x = (const float*)d_in[0];
    float* out = (float*)d_out;

    unsigned* spec = (unsigned*)d_ws;   // 32*16384*4 B = 2 MiB (bf16x2)
    float4* rec = (float4*)((char*)d_ws + (size_t)M_WAVE * FFT_N * sizeof(unsigned));

    fwd_fft_kernel<<<128, 256, 0, stream>>>(x, spec);
    pair_kernel<<<NPAIR, THREADS, 0, stream>>>(spec, rec);
    final_kernel<<<1, 64, 0, stream>>>(rec, out);
}

// Round 10
// 56.167 us; speedup vs baseline: 1.1343x; 1.1343x over previous
//
#include <hip/hip_runtime.h>
#include <math.h>

#define M_WAVE 32
#define NLEN 8192
#define FFT_N 16384
#define NPAIR 528   // 496 cross (blocks 0..495) + 32 autos (blocks 496..527)

#define TWOPI_F 6.28318530717958647692f

__device__ __forceinline__ float2 cadd(float2 a, float2 b){return make_float2(a.x+b.x, a.y+b.y);}
__device__ __forceinline__ float2 csub(float2 a, float2 b){return make_float2(a.x-b.x, a.y-b.y);}
__device__ __forceinline__ float2 cmul(float2 a, float2 b){return make_float2(a.x*b.x-a.y*b.y, a.x*b.y+a.y*b.x);}
__device__ __forceinline__ float2 mul_i (float2 a){return make_float2(-a.y,  a.x);}
__device__ __forceinline__ float2 mul_mi(float2 a){return make_float2( a.y, -a.x);}

// bf16x2 pack/unpack: one complex float2 <-> one u32 (re=low16, im=high16)
__device__ __forceinline__ unsigned pkc(float2 v){
    unsigned r;
    asm("v_cvt_pk_bf16_f32 %0, %1, %2" : "=v"(r) : "v"(v.x), "v"(v.y));
    return r;
}
__device__ __forceinline__ float2 upkc(unsigned u){
    return make_float2(__uint_as_float(u << 16), __uint_as_float(u & 0xFFFF0000u));
}

__device__ __forceinline__ float2 dpp_xor1(float2 v){
    float2 r;
    r.x = __int_as_float(__builtin_amdgcn_mov_dpp(__float_as_int(v.x), 0xB1, 0xF, 0xF, true));
    r.y = __int_as_float(__builtin_amdgcn_mov_dpp(__float_as_int(v.y), 0xB1, 0xF, 0xF, true));
    return r;
}
__device__ __forceinline__ float2 dpp_xor2(float2 v){
    float2 r;
    r.x = __int_as_float(__builtin_amdgcn_mov_dpp(__float_as_int(v.x), 0x4E, 0xF, 0xF, true));
    r.y = __int_as_float(__builtin_amdgcn_mov_dpp(__float_as_int(v.y), 0x4E, 0xF, 0xF, true));
    return r;
}

__device__ __forceinline__ float waveReduceMax(float v) {
    #pragma unroll
    for (int off = 32; off > 0; off >>= 1) v = fmaxf(v, __shfl_down(v, off, 64));
    return v;
}
__device__ __forceinline__ float waveReduceSum(float v) {
    #pragma unroll
    for (int off = 32; off > 0; off >>= 1) v += __shfl_down(v, off, 64);
    return v;
}

// ---------- classic dft16 (natural order) -- fwd kernel only ----------
template<int SGN>
__device__ __forceinline__ void dft16_tail(float2 w[16], float2 v[16]){
    const float C1 = 0.923879532511286756f;
    const float S1 = 0.382683432365089772f;
    const float R2 = 0.707106781186547524f;
    const float G = (SGN < 0) ? -1.0f : 1.0f;
    w[5]  = cmul(w[5],  make_float2( C1,  G*S1));
    w[6]  = cmul(w[6],  make_float2( R2,  G*R2));
    w[7]  = cmul(w[7],  make_float2( S1,  G*C1));
    w[9]  = cmul(w[9],  make_float2( R2,  G*R2));
    w[10] = (SGN<0) ? mul_mi(w[10]) : mul_i(w[10]);
    w[11] = cmul(w[11], make_float2(-R2,  G*R2));
    w[13] = cmul(w[13], make_float2( S1,  G*C1));
    w[14] = cmul(w[14], make_float2(-R2,  G*R2));
    w[15] = cmul(w[15], make_float2(-C1, -G*S1));
    #pragma unroll
    for (int k0 = 0; k0 < 4; ++k0){
        float2 a = w[k0*4+0], b = w[k0*4+1], c = w[k0*4+2], d = w[k0*4+3];
        float2 t0 = cadd(a,c), t1 = csub(a,c), t2 = cadd(b,d), t3 = csub(b,d);
        float2 j3 = (SGN < 0) ? mul_mi(t3) : mul_i(t3);
        v[k0]    = cadd(t0,t2);
        v[k0+4]  = cadd(t1,j3);
        v[k0+8]  = csub(t0,t2);
        v[k0+12] = csub(t1,j3);
    }
}

template<int SGN>
__device__ __forceinline__ void dft16(float2 v[16]){
    float2 w[16];
    #pragma unroll
    for (int n0 = 0; n0 < 4; ++n0){
        float2 a = v[n0], b = v[n0+4], c = v[n0+8], d = v[n0+12];
        float2 t0 = cadd(a,c), t1 = csub(a,c), t2 = cadd(b,d), t3 = csub(b,d);
        float2 j3 = (SGN < 0) ? mul_mi(t3) : mul_i(t3);
        w[n0]    = cadd(t0,t2);
        w[4+n0]  = cadd(t1,j3);
        w[8+n0]  = csub(t0,t2);
        w[12+n0] = csub(t1,j3);
    }
    dft16_tail<SGN>(w, v);
}

// forward DFT16 with inputs 8..15 == 0 (zero-padded), SGN=-1
__device__ __forceinline__ void dft16_zero8(float2 v[16]){
    float2 w[16];
    #pragma unroll
    for (int n0 = 0; n0 < 4; ++n0){
        float2 a = v[n0], b = v[n0+4];
        w[n0]    = cadd(a,b);
        w[4+n0]  = make_float2(a.x + b.y, a.y - b.x);  // a - i b
        w[8+n0]  = csub(a,b);
        w[12+n0] = make_float2(a.x - b.y, a.y + b.x);  // a + i b
    }
    dft16_tail<-1>(w, v);
}

// ---------- in-place dft16, digit-reversed output: slot s holds y[4*(s&3)+(s>>2)].
template<int SGN>
__device__ __forceinline__ void dft16_ip(float2 v[16]){
    const float C1 = 0.923879532511286756f;
    const float S1 = 0.382683432365089772f;
    const float R2 = 0.707106781186547524f;
    const float G = (SGN < 0) ? -1.0f : 1.0f;
    #pragma unroll
    for (int n1 = 0; n1 < 4; ++n1){
        float2 a = v[n1], b = v[n1+4], c = v[n1+8], d = v[n1+12];
        float2 t0 = cadd(a,c), t1 = csub(a,c), t2 = cadd(b,d), t3 = csub(b,d);
        float2 j3 = (SGN < 0) ? mul_mi(t3) : mul_i(t3);
        v[n1]    = cadd(t0,t2);
        v[n1+4]  = cadd(t1,j3);
        v[n1+8]  = csub(t0,t2);
        v[n1+12] = csub(t1,j3);
    }
    v[5]  = cmul(v[5],  make_float2( C1,  G*S1));
    v[6]  = cmul(v[6],  make_float2( R2,  G*R2));
    v[7]  = cmul(v[7],  make_float2( S1,  G*C1));
    v[9]  = cmul(v[9],  make_float2( R2,  G*R2));
    v[10] = (SGN<0) ? mul_mi(v[10]) : mul_i(v[10]);
    v[11] = cmul(v[11], make_float2(-R2,  G*R2));
    v[13] = cmul(v[13], make_float2( S1,  G*C1));
    v[14] = cmul(v[14], make_float2(-R2,  G*R2));
    v[15] = cmul(v[15], make_float2(-C1, -G*S1));
    #pragma unroll
    for (int kl = 0; kl < 4; ++kl){
        float2 a = v[4*kl], b = v[4*kl+1], c = v[4*kl+2], d = v[4*kl+3];
        float2 t0 = cadd(a,c), t1 = csub(a,c), t2 = cadd(b,d), t3 = csub(b,d);
        float2 j3 = (SGN < 0) ? mul_mi(t3) : mul_i(t3);
        v[4*kl]   = cadd(t0,t2);
        v[4*kl+1] = cadd(t1,j3);
        v[4*kl+2] = csub(t0,t2);
        v[4*kl+3] = csub(t1,j3);
    }
}

template<int SGN>
__device__ __forceinline__ void twchain16(float2 v[16], float theta){
    float th = (SGN < 0) ? -theta : theta;
    float s1,c1; __sincosf(th, &s1, &c1);
    float s4,c4; __sincosf(4.0f*th, &s4, &c4);
    float2 w1 = make_float2(c1,s1), w4 = make_float2(c4,s4);
    float2 lo2 = cmul(w1,w1), lo3 = cmul(lo2,w1);
    float2 hi2 = cmul(w4,w4), hi3 = cmul(hi2,w4);
    float2 lo[4] = {make_float2(1.f,0.f), w1, lo2, lo3};
    float2 hi[4] = {make_float2(1.f,0.f), w4, hi2, hi3};
    #pragma unroll
    for (int s = 1; s < 16; ++s){
        v[s] = cmul(v[s], cmul(hi[s>>2], lo[s&3]));
    }
}

__device__ __forceinline__ int L1swz(int e){
    return (e & ~63) | (((e & 63) + ((e >> 6) & 15)) & 63);
}

// Forward FFT: 64 blocks = 32 m x 2 halves, 512 threads, fp32 LDS 64 KiB.
// Stage A: 2 columns/thread (2x redundancy, keep 8 chunks). B/C: wave wv = chunk wv.
// 8 waves/CU = 2 waves/EU on 64 CUs. bf16 spec store, same layout pair reads.
__global__ __launch_bounds__(512, 2) void fwd_fft_kernel(const float* __restrict__ x,
                                                         unsigned* __restrict__ spec) {
    __shared__ float2 X8[8192];  // 64 KiB
    const int bx = blockIdx.x, m = bx >> 1, hf = bx & 1;
    const int tid = threadIdx.x;

    // Stage A: columns j = tid, tid+512; keep outputs s = 8hf..8hf+7
    #pragma unroll 1
    for (int cc = 0; cc < 2; ++cc){
        const int j = cc*512 + tid;
        float2 v[16];
        #pragma unroll
        for (int s = 0; s < 8; ++s){
            float ph = TWOPI_F * x[m*NLEN + s*1024 + j];
            float sn,cs; __sincosf(ph,&sn,&cs);
            v[s] = make_float2(cs,sn);
        }
        dft16_zero8(v);
        const float th = TWOPI_F * (float)j / 16384.0f;
        float sb,cb; __sincosf(-(float)(8*hf)*th, &sb, &cb);
        float ss,cs2; __sincosf(-th, &ss, &cs2);
        float2 wcur = make_float2(cb,sb), wstep = make_float2(cs2,ss);
        #pragma unroll
        for (int d = 0; d < 8; ++d){
            X8[d*1024 + L1swz(j)] = cmul(v[8*hf + d], wcur);
            wcur = cmul(wcur, wstep);
        }
    }
    __syncthreads();

    // Stage B: wave wv = local chunk wv (global chunk 8hf+wv)
    const int wv = tid >> 6, jB = tid & 63;
    float2 v[16];
    #pragma unroll
    for (int t = 0; t < 16; ++t) v[t] = X8[wv*1024 + t*64 + ((jB + t) & 63)];
    dft16<-1>(v);
    twchain16<-1>(v, TWOPI_F * (float)jB / 1024.0f);
    #pragma unroll
    for (int sp = 0; sp < 16; ++sp) X8[wv*1024 + sp*64 + ((jB + 4*sp) & 63)] = v[sp];
    // no barrier: stage C reads only this wave's chunk

    // Stage C: DFT16 + tw W64 + 4-lane DPP DFT4, bf16 store
    {
        const int bl = (tid & 63) >> 2, jC = tid & 3;
        #pragma unroll
        for (int a = 0; a < 16; ++a)
            v[a] = X8[wv*1024 + bl*64 + ((4*a + jC + 4*bl) & 63)];
        dft16<-1>(v);
        twchain16<-1>(v, TWOPI_F * (float)jC / 64.0f);
        const bool odd1 = (jC & 1) != 0;
        const bool odd2 = (jC & 2) != 0;
        #pragma unroll
        for (int e = 0; e < 16; ++e){
            float2 p = dpp_xor2(v[e]);
            float2 t = odd2 ? csub(p, v[e]) : cadd(v[e], p);
            float2 q = dpp_xor1(t);
            float2 re = odd1 ? csub(q, t) : cadd(t, q);
            float2 ro = odd1 ? cadd(q, mul_i(t)) : cadd(t, mul_mi(q));
            v[e] = odd2 ? ro : re;
        }
        const int u = ((jC & 1) << 1) | (jC >> 1);
        uint4* dst = (uint4*)(spec + (size_t)m*FFT_N + (8*hf + wv)*1024 + bl*64 + u*16);
        #pragma unroll
        for (int e = 0; e < 4; ++e)
            dst[e] = make_uint4(pkc(v[4*e]), pkc(v[4*e+1]), pkc(v[4*e+2]), pkc(v[4*e+3]));
    }
}

// Pair kernel: 512 threads run the verified 1024-thread network twice
// (pass p: original column tid+512p). Wave wv owns chunks {wv, wv+8} in both
// C' and B' (wave-local, no barrier). 64 KiB bf16 LDS -> 2 blocks/CU at
// launch_bounds(512,4) = 128-VGPR budget (no spills, unlike R8/R9's 64).
__global__ __launch_bounds__(512, 4) void pair_kernel(const unsigned* __restrict__ spec,
                                                      float4* __restrict__ rec) {
    __shared__ unsigned X[FFT_N];  // 64 KiB, bf16x2 per element
    const int r = blockIdx.x, tid = threadIdx.x;
    const bool is_auto = (r >= 496);
    int a, b, rec_idx;
    if (is_auto){
        a = b = r - 496;
        rec_idx = r - 496;           // autos -> rec[0..31]
    } else {
        int t = r; a = 0; int rem = M_WAVE - 1;
        while (t >= rem){ t -= rem; ++a; rem = M_WAVE - 1 - a; }
        b = a + 1 + t;
        rec_idx = M_WAVE + r;        // cross -> rec[32..527]
    }
    const int jC = tid & 3;
    const int u = ((jC & 1) << 1) | (jC >> 1);
    const bool odd1 = (jC & 1) != 0;
    const bool odd2 = (jC & 2) != 0;

    // Stage C' (both passes): load product, adjoint lane-DFT4, tw, dft16_ip, store
    #pragma unroll
    for (int p = 0; p < 2; ++p){
        const int blk = (tid >> 2) + 128*p;   // [0,256)
        float2 v[16];
        const uint4* pa = (const uint4*)(spec + (size_t)a*FFT_N + blk*64 + u*16);
        const uint4* pb = (const uint4*)(spec + (size_t)b*FFT_N + blk*64 + u*16);
        #pragma unroll
        for (int e = 0; e < 4; ++e){
            uint4 A = pa[e], B = pb[e];
            float2 a0 = upkc(A.x), a1 = upkc(A.y), a2 = upkc(A.z), a3 = upkc(A.w);
            float2 b0 = upkc(B.x), b1 = upkc(B.y), b2 = upkc(B.z), b3 = upkc(B.w);
            v[4*e+0] = make_float2(b0.x*a0.x + b0.y*a0.y, b0.y*a0.x - b0.x*a0.y);
            v[4*e+1] = make_float2(b1.x*a1.x + b1.y*a1.y, b1.y*a1.x - b1.x*a1.y);
            v[4*e+2] = make_float2(b2.x*a2.x + b2.y*a2.y, b2.y*a2.x - b2.x*a2.y);
            v[4*e+3] = make_float2(b3.x*a3.x + b3.y*a3.y, b3.y*a3.x - b3.x*a3.y);
        }
        #pragma unroll
        for (int e = 0; e < 16; ++e){
            float2 q = dpp_xor1(v[e]);
            float2 t = odd1 ? csub(q, v[e]) : cadd(v[e], q);
            float2 pp = dpp_xor2(t);
            float2 re = odd2 ? csub(pp, t) : cadd(t, pp);
            float2 ro = odd2 ? csub(pp, mul_i(t)) : cadd(t, mul_i(pp));
            v[e] = odd1 ? ro : re;
        }
        twchain16<+1>(v, TWOPI_F * (float)jC / 64.0f);
        dft16_ip<+1>(v);
        const int rot = 4*(blk & 15);
        #pragma unroll
        for (int s = 0; s < 16; ++s){
            const int t = 4*(s&3) + (s>>2);   // digit held in slot s
            X[blk*64 + ((4*t + jC + rot) & 63)] = pkc(v[s]);
        }
    }
    // Stage B' (both passes; wave-local, no barrier needed after C')
    const int wv = tid >> 6, jB = tid & 63;
    #pragma unroll
    for (int p = 0; p < 2; ++p){
        const int sB = wv + 8*p;
        float2 v[16];
        #pragma unroll
        for (int sp = 0; sp < 16; ++sp) v[sp] = upkc(X[sB*1024 + sp*64 + ((jB + 4*sp) & 63)]);
        twchain16<+1>(v, TWOPI_F * (float)jB / 1024.0f);
        dft16_ip<+1>(v);
        #pragma unroll
        for (int s = 0; s < 16; ++s){
            const int t = 4*(s&3) + (s>>2);
            X[sB*1024 + t*64 + ((jB + t) & 63)] = pkc(v[s]);
        }
    }
    __syncthreads();   // cross-wave: A' gathers from all chunks

    // Stage A' (both passes) + stats. Lag n = rev(s)*1024 + (tid+512p).
    const float CSCALE = 0.1f / (16384.0f * 16384.0f);
    float uval[2][16];
    float lm = 0.f, lsum = 0.f;
    #pragma unroll
    for (int p = 0; p < 2; ++p){
        const int tp = tid + 512*p;
        const int baseA = L1swz(tp);
        float2 v[16];
        #pragma unroll
        for (int s = 0; s < 16; ++s) v[s] = upkc(X[s*1024 + baseA]);
        twchain16<+1>(v, TWOPI_F * (float)tp / 16384.0f);
        dft16_ip<+1>(v);
        const bool j0 = (tp == 0);
        #pragma unroll
        for (int s = 0; s < 16; ++s){
            const int t = 4*(s&3) + (s>>2);
            float uu = CSCALE * (v[s].x*v[s].x + v[s].y*v[s].y);
            uval[p][s] = uu;
            if (is_auto){
                bool valid = (t > 8) || ((t == 8) && !j0);
                if (valid){ lm = fmaxf(lm, uu); lsum += uu; }
            } else {
                bool inv = (t == 8) && j0;
                if (!inv){ lm = fmaxf(lm, uu); lsum += uu; }
                if (t == 0 && j0) lsum += uu;
            }
        }
    }
    __syncthreads();  // X reads done; reuse as scratch

    float* scratch = (float*)X;
    const int lane = tid & 63, wvv = tid >> 6;   // 8 waves
    float wm = waveReduceMax(lm);
    float wsm = waveReduceSum(lsum);
    if (lane == 0){ scratch[wvv] = wm; scratch[8+wvv] = wsm; }
    __syncthreads();
    float m_b = scratch[0], sumu = scratch[8];
    #pragma unroll
    for (int i = 1; i < 8; ++i){ m_b = fmaxf(m_b, scratch[i]); sumu += scratch[8+i]; }

    const float invTN2 = 1.0f / 67108.864f;   // 1/(T*N*N)
    float le = 0.f;
    #pragma unroll
    for (int p = 0; p < 2; ++p){
        const bool j0 = (p == 0) && (tid == 0);
        #pragma unroll
        for (int s = 0; s < 16; ++s){
            const int t = 4*(s&3) + (s>>2);
            float ex = __expf((uval[p][s] - m_b) * invTN2);
            if (is_auto){
                bool valid = (t > 8) || ((t == 8) && !j0);
                if (valid) le += ex;
            } else {
                bool inv = (t == 8) && j0;
                if (!inv) le += ((t == 0 && j0) ? 2.f : 1.f) * ex;
            }
        }
    }
    float wle = waveReduceSum(le);
    if (lane == 0) scratch[16+wvv] = wle;
    __syncthreads();
    if (tid == 0){
        float sb2 = 0.f;
        #pragma unroll
        for (int i = 0; i < 8; ++i) sb2 += scratch[16+i];
        rec[rec_idx] = make_float4(m_b, sumu, sb2, 0.f);
    }
}

// Merge 528 records -> 7 outputs. Single wave, shuffle-only, deterministic.
__global__ __launch_bounds__(64) void final_kernel(const float4* __restrict__ rec,
                                                   float* __restrict__ out) {
    const int lane = threadIdx.x;
    float mA = 0.f, mC = 0.f;
    for (int r = lane; r < NPAIR; r += 64){
        float mx = rec[r].x;
        if (r < M_WAVE) mA = fmaxf(mA, mx); else mC = fmaxf(mC, mx);
    }
    #pragma unroll
    for (int off = 32; off > 0; off >>= 1){
        mA = fmaxf(mA, __shfl_xor(mA, off, 64));
        mC = fmaxf(mC, __shfl_xor(mC, off, 64));
    }
    const float Mall = fmaxf(mA, mC);
    const float invTN2f = 1.0f / 67108.864f;
    double S = 0.0, sA = 0.0, sC = 0.0;
    for (int r = lane; r < NPAIR; r += 64){
        float4 rv = rec[r];
        S += (double)rv.z * (double)__expf((rv.x - Mall)*invTN2f);
        if (r < M_WAVE) sA += (double)rv.y; else sC += (double)rv.y;
    }
    #pragma unroll
    for (int off = 32; off > 0; off >>= 1){
        S  += __shfl_xor(S,  off, 64);
        sA += __shfl_xor(sA, off, 64);
        sC += __shfl_xor(sC, off, 64);
    }
    if (lane == 0){
        const double invN2 = 1.0/67108864.0;
        out[0] = (float)((double)Mall*invN2 + 1e-3*log(S));
        out[1] = (float)((double)Mall*invN2);
        out[2] = mA;
        out[3] = mC;
        out[4] = (float)((sA + sC)*invN2);
        out[5] = (float)sA;
        out[6] = (float)sC;
    }
}

extern "C" void kernel_launch(void* const* d_in, const int* in_sizes, int n_in,
                              void* d_out, int out_size, void* d_ws, size_t ws_size,
                              hipStream_t stream) {
    (void)in_sizes; (void)n_in; (void)out_size; (void)ws_size;
    const float* x = (const float*)d_in[0];
    float* out = (float*)d_out;

    unsigned* spec = (unsigned*)d_ws;   // 32*16384*4 B = 2 MiB (bf16x2)
    float4* rec = (float4*)((char*)d_ws + (size_t)M_WAVE * FFT_N * sizeof(unsigned));

    fwd_fft_kernel<<<64, 512, 0, stream>>>(x, spec);
    pair_kernel<<<NPAIR, 512, 0, stream>>>(spec, rec);
    final_kernel<<<1, 64, 0, stream>>>(rec, out);
}

// Round 11
// 52.178 us; speedup vs baseline: 1.2210x; 1.0765x over previous
//
#include <hip/hip_runtime.h>
#include <math.h>

#define M_WAVE 32
#define NLEN 8192
#define FFT_N 16384
#define NPAIR 528   // rec entries: 32 autos (rec[0..31]) + 496 cross (rec[32..527])

#define TWOPI_F 6.28318530717958647692f

__device__ __forceinline__ float2 cadd(float2 a, float2 b){return make_float2(a.x+b.x, a.y+b.y);}
__device__ __forceinline__ float2 csub(float2 a, float2 b){return make_float2(a.x-b.x, a.y-b.y);}
__device__ __forceinline__ float2 cmul(float2 a, float2 b){return make_float2(a.x*b.x-a.y*b.y, a.x*b.y+a.y*b.x);}
__device__ __forceinline__ float2 mul_i (float2 a){return make_float2(-a.y,  a.x);}
__device__ __forceinline__ float2 mul_mi(float2 a){return make_float2( a.y, -a.x);}

// bf16x2 pack/unpack: one complex float2 <-> one u32 (re=low16, im=high16)
__device__ __forceinline__ unsigned pkc(float2 v){
    unsigned r;
    asm("v_cvt_pk_bf16_f32 %0, %1, %2" : "=v"(r) : "v"(v.x), "v"(v.y));
    return r;
}
__device__ __forceinline__ float2 upkc(unsigned u){
    return make_float2(__uint_as_float(u << 16), __uint_as_float(u & 0xFFFF0000u));
}

__device__ __forceinline__ float2 dpp_xor1(float2 v){
    float2 r;
    r.x = __int_as_float(__builtin_amdgcn_mov_dpp(__float_as_int(v.x), 0xB1, 0xF, 0xF, true));
    r.y = __int_as_float(__builtin_amdgcn_mov_dpp(__float_as_int(v.y), 0xB1, 0xF, 0xF, true));
    return r;
}
__device__ __forceinline__ float2 dpp_xor2(float2 v){
    float2 r;
    r.x = __int_as_float(__builtin_amdgcn_mov_dpp(__float_as_int(v.x), 0x4E, 0xF, 0xF, true));
    r.y = __int_as_float(__builtin_amdgcn_mov_dpp(__float_as_int(v.y), 0x4E, 0xF, 0xF, true));
    return r;
}

__device__ __forceinline__ float waveReduceMax(float v) {
    #pragma unroll
    for (int off = 32; off > 0; off >>= 1) v = fmaxf(v, __shfl_down(v, off, 64));
    return v;
}
__device__ __forceinline__ float waveReduceSum(float v) {
    #pragma unroll
    for (int off = 32; off > 0; off >>= 1) v += __shfl_down(v, off, 64);
    return v;
}

// ---------- classic dft16 (natural order) -- fwd kernel only ----------
template<int SGN>
__device__ __forceinline__ void dft16_tail(float2 w[16], float2 v[16]){
    const float C1 = 0.923879532511286756f;
    const float S1 = 0.382683432365089772f;
    const float R2 = 0.707106781186547524f;
    const float G = (SGN < 0) ? -1.0f : 1.0f;
    w[5]  = cmul(w[5],  make_float2( C1,  G*S1));
    w[6]  = cmul(w[6],  make_float2( R2,  G*R2));
    w[7]  = cmul(w[7],  make_float2( S1,  G*C1));
    w[9]  = cmul(w[9],  make_float2( R2,  G*R2));
    w[10] = (SGN<0) ? mul_mi(w[10]) : mul_i(w[10]);
    w[11] = cmul(w[11], make_float2(-R2,  G*R2));
    w[13] = cmul(w[13], make_float2( S1,  G*C1));
    w[14] = cmul(w[14], make_float2(-R2,  G*R2));
    w[15] = cmul(w[15], make_float2(-C1, -G*S1));
    #pragma unroll
    for (int k0 = 0; k0 < 4; ++k0){
        float2 a = w[k0*4+0], b = w[k0*4+1], c = w[k0*4+2], d = w[k0*4+3];
        float2 t0 = cadd(a,c), t1 = csub(a,c), t2 = cadd(b,d), t3 = csub(b,d);
        float2 j3 = (SGN < 0) ? mul_mi(t3) : mul_i(t3);
        v[k0]    = cadd(t0,t2);
        v[k0+4]  = cadd(t1,j3);
        v[k0+8]  = csub(t0,t2);
        v[k0+12] = csub(t1,j3);
    }
}

template<int SGN>
__device__ __forceinline__ void dft16(float2 v[16]){
    float2 w[16];
    #pragma unroll
    for (int n0 = 0; n0 < 4; ++n0){
        float2 a = v[n0], b = v[n0+4], c = v[n0+8], d = v[n0+12];
        float2 t0 = cadd(a,c), t1 = csub(a,c), t2 = cadd(b,d), t3 = csub(b,d);
        float2 j3 = (SGN < 0) ? mul_mi(t3) : mul_i(t3);
        w[n0]    = cadd(t0,t2);
        w[4+n0]  = cadd(t1,j3);
        w[8+n0]  = csub(t0,t2);
        w[12+n0] = csub(t1,j3);
    }
    dft16_tail<SGN>(w, v);
}

// forward DFT16 with inputs 8..15 == 0 (zero-padded), SGN=-1
__device__ __forceinline__ void dft16_zero8(float2 v[16]){
    float2 w[16];
    #pragma unroll
    for (int n0 = 0; n0 < 4; ++n0){
        float2 a = v[n0], b = v[n0+4];
        w[n0]    = cadd(a,b);
        w[4+n0]  = make_float2(a.x + b.y, a.y - b.x);  // a - i b
        w[8+n0]  = csub(a,b);
        w[12+n0] = make_float2(a.x - b.y, a.y + b.x);  // a + i b
    }
    dft16_tail<-1>(w, v);
}

// ---------- in-place dft16, digit-reversed output: slot s holds y[4*(s&3)+(s>>2)].
template<int SGN>
__device__ __forceinline__ void dft16_ip(float2 v[16]){
    const float C1 = 0.923879532511286756f;
    const float S1 = 0.382683432365089772f;
    const float R2 = 0.707106781186547524f;
    const float G = (SGN < 0) ? -1.0f : 1.0f;
    #pragma unroll
    for (int n1 = 0; n1 < 4; ++n1){
        float2 a = v[n1], b = v[n1+4], c = v[n1+8], d = v[n1+12];
        float2 t0 = cadd(a,c), t1 = csub(a,c), t2 = cadd(b,d), t3 = csub(b,d);
        float2 j3 = (SGN < 0) ? mul_mi(t3) : mul_i(t3);
        v[n1]    = cadd(t0,t2);
        v[n1+4]  = cadd(t1,j3);
        v[n1+8]  = csub(t0,t2);
        v[n1+12] = csub(t1,j3);
    }
    v[5]  = cmul(v[5],  make_float2( C1,  G*S1));
    v[6]  = cmul(v[6],  make_float2( R2,  G*R2));
    v[7]  = cmul(v[7],  make_float2( S1,  G*C1));
    v[9]  = cmul(v[9],  make_float2( R2,  G*R2));
    v[10] = (SGN<0) ? mul_mi(v[10]) : mul_i(v[10]);
    v[11] = cmul(v[11], make_float2(-R2,  G*R2));
    v[13] = cmul(v[13], make_float2( S1,  G*C1));
    v[14] = cmul(v[14], make_float2(-R2,  G*R2));
    v[15] = cmul(v[15], make_float2(-C1, -G*S1));
    #pragma unroll
    for (int kl = 0; kl < 4; ++kl){
        float2 a = v[4*kl], b = v[4*kl+1], c = v[4*kl+2], d = v[4*kl+3];
        float2 t0 = cadd(a,c), t1 = csub(a,c), t2 = cadd(b,d), t3 = csub(b,d);
        float2 j3 = (SGN < 0) ? mul_mi(t3) : mul_i(t3);
        v[4*kl]   = cadd(t0,t2);
        v[4*kl+1] = cadd(t1,j3);
        v[4*kl+2] = csub(t0,t2);
        v[4*kl+3] = csub(t1,j3);
    }
}

template<int SGN>
__device__ __forceinline__ void twchain16(float2 v[16], float theta){
    float th = (SGN < 0) ? -theta : theta;
    float s1,c1; __sincosf(th, &s1, &c1);
    float s4,c4; __sincosf(4.0f*th, &s4, &c4);
    float2 w1 = make_float2(c1,s1), w4 = make_float2(c4,s4);
    float2 lo2 = cmul(w1,w1), lo3 = cmul(lo2,w1);
    float2 hi2 = cmul(w4,w4), hi3 = cmul(hi2,w4);
    float2 lo[4] = {make_float2(1.f,0.f), w1, lo2, lo3};
    float2 hi[4] = {make_float2(1.f,0.f), w4, hi2, hi3};
    #pragma unroll
    for (int s = 1; s < 16; ++s){
        v[s] = cmul(v[s], cmul(hi[s>>2], lo[s&3]));
    }
}

__device__ __forceinline__ int L1swz(int e){
    return (e & ~63) | (((e & 63) + ((e >> 6) & 15)) & 63);
}

// Forward FFT: 64 blocks = 32 m x 2 halves, 512 threads, fp32 LDS 64 KiB (R10, verified).
__global__ __launch_bounds__(512, 2) void fwd_fft_kernel(const float* __restrict__ x,
                                                         unsigned* __restrict__ spec) {
    __shared__ float2 X8[8192];  // 64 KiB
    const int bx = blockIdx.x, m = bx >> 1, hf = bx & 1;
    const int tid = threadIdx.x;

    #pragma unroll 1
    for (int cc = 0; cc < 2; ++cc){
        const int j = cc*512 + tid;
        float2 v[16];
        #pragma unroll
        for (int s = 0; s < 8; ++s){
            float ph = TWOPI_F * x[m*NLEN + s*1024 + j];
            float sn,cs; __sincosf(ph,&sn,&cs);
            v[s] = make_float2(cs,sn);
        }
        dft16_zero8(v);
        const float th = TWOPI_F * (float)j / 16384.0f;
        float sb,cb; __sincosf(-(float)(8*hf)*th, &sb, &cb);
        float ss,cs2; __sincosf(-th, &ss, &cs2);
        float2 wcur = make_float2(cb,sb), wstep = make_float2(cs2,ss);
        #pragma unroll
        for (int d = 0; d < 8; ++d){
            X8[d*1024 + L1swz(j)] = cmul(v[8*hf + d], wcur);
            wcur = cmul(wcur, wstep);
        }
    }
    __syncthreads();

    const int wv = tid >> 6, jB = tid & 63;
    float2 v[16];
    #pragma unroll
    for (int t = 0; t < 16; ++t) v[t] = X8[wv*1024 + t*64 + ((jB + t) & 63)];
    dft16<-1>(v);
    twchain16<-1>(v, TWOPI_F * (float)jB / 1024.0f);
    #pragma unroll
    for (int sp = 0; sp < 16; ++sp) X8[wv*1024 + sp*64 + ((jB + 4*sp) & 63)] = v[sp];
    // no barrier: stage C reads only this wave's chunk

    {
        const int bl = (tid & 63) >> 2, jC = tid & 3;
        #pragma unroll
        for (int a = 0; a < 16; ++a)
            v[a] = X8[wv*1024 + bl*64 + ((4*a + jC + 4*bl) & 63)];
        dft16<-1>(v);
        twchain16<-1>(v, TWOPI_F * (float)jC / 64.0f);
        const bool odd1 = (jC & 1) != 0;
        const bool odd2 = (jC & 2) != 0;
        #pragma unroll
        for (int e = 0; e < 16; ++e){
            float2 p = dpp_xor2(v[e]);
            float2 t = odd2 ? csub(p, v[e]) : cadd(v[e], p);
            float2 q = dpp_xor1(t);
            float2 re = odd1 ? csub(q, t) : cadd(t, q);
            float2 ro = odd1 ? cadd(q, mul_i(t)) : cadd(t, mul_mi(q));
            v[e] = odd2 ? ro : re;
        }
        const int u = ((jC & 1) << 1) | (jC >> 1);
        uint4* dst = (uint4*)(spec + (size_t)m*FFT_N + (8*hf + wv)*1024 + bl*64 + u*16);
        #pragma unroll
        for (int e = 0; e < 4; ++e)
            dst[e] = make_uint4(pkc(v[4*e]), pkc(v[4*e+1]), pkc(v[4*e+2]), pkc(v[4*e+3]));
    }
}

// Pair kernel: 512 blocks (exactly 2/CU co-resident, one scheduling round).
// Blocks 0..495: cross pair (both orderings). Blocks 496..511: TWO autos packed
// into one IFFT via z[k] = |S_a|^2 + i*|S_b|^2 (sigma_auto conj-symmetric);
// recovered by lag-reversal exchange through LDS after the transform.
__global__ __launch_bounds__(512, 4) void pair_kernel(const unsigned* __restrict__ spec,
                                                      float4* __restrict__ rec) {
    __shared__ unsigned X[FFT_N];  // 64 KiB, bf16x2 per element
    __shared__ float scr2[64];
    const int r = blockIdx.x, tid = threadIdx.x;
    const bool is_packed = (r >= 496);
    int a, b;
    if (is_packed){
        const int k = r - 496; a = 2*k; b = 2*k + 1;
    } else {
        int t = r; a = 0; int rem = M_WAVE - 1;
        while (t >= rem){ t -= rem; ++a; rem = M_WAVE - 1 - a; }
        b = a + 1 + t;
    }
    const int jC = tid & 3;
    const int u = ((jC & 1) << 1) | (jC >> 1);
    const bool odd1 = (jC & 1) != 0;
    const bool odd2 = (jC & 2) != 0;

    // Stage C' (both passes): load, adjoint lane-DFT4, tw, dft16_ip, store
    #pragma unroll
    for (int p = 0; p < 2; ++p){
        const int blk = (tid >> 2) + 128*p;   // [0,256)
        float2 v[16];
        const uint4* pa = (const uint4*)(spec + (size_t)a*FFT_N + blk*64 + u*16);
        const uint4* pb = (const uint4*)(spec + (size_t)b*FFT_N + blk*64 + u*16);
        #pragma unroll
        for (int e = 0; e < 4; ++e){
            uint4 A = pa[e], B = pb[e];
            float2 a0 = upkc(A.x), a1 = upkc(A.y), a2 = upkc(A.z), a3 = upkc(A.w);
            float2 b0 = upkc(B.x), b1 = upkc(B.y), b2 = upkc(B.z), b3 = upkc(B.w);
            if (is_packed){
                v[4*e+0] = make_float2(a0.x*a0.x + a0.y*a0.y, b0.x*b0.x + b0.y*b0.y);
                v[4*e+1] = make_float2(a1.x*a1.x + a1.y*a1.y, b1.x*b1.x + b1.y*b1.y);
                v[4*e+2] = make_float2(a2.x*a2.x + a2.y*a2.y, b2.x*b2.x + b2.y*b2.y);
                v[4*e+3] = make_float2(a3.x*a3.x + a3.y*a3.y, b3.x*b3.x + b3.y*b3.y);
            } else {
                v[4*e+0] = make_float2(b0.x*a0.x + b0.y*a0.y, b0.y*a0.x - b0.x*a0.y);
                v[4*e+1] = make_float2(b1.x*a1.x + b1.y*a1.y, b1.y*a1.x - b1.x*a1.y);
                v[4*e+2] = make_float2(b2.x*a2.x + b2.y*a2.y, b2.y*a2.x - b2.x*a2.y);
                v[4*e+3] = make_float2(b3.x*a3.x + b3.y*a3.y, b3.y*a3.x - b3.x*a3.y);
            }
        }
        #pragma unroll
        for (int e = 0; e < 16; ++e){
            float2 q = dpp_xor1(v[e]);
            float2 t = odd1 ? csub(q, v[e]) : cadd(v[e], q);
            float2 pp = dpp_xor2(t);
            float2 re = odd2 ? csub(pp, t) : cadd(t, pp);
            float2 ro = odd2 ? csub(pp, mul_i(t)) : cadd(t, mul_i(pp));
            v[e] = odd1 ? ro : re;
        }
        twchain16<+1>(v, TWOPI_F * (float)jC / 64.0f);
        dft16_ip<+1>(v);
        const int rot = 4*(blk & 15);
        #pragma unroll
        for (int s = 0; s < 16; ++s){
            const int t = 4*(s&3) + (s>>2);   // digit held in slot s
            X[blk*64 + ((4*t + jC + rot) & 63)] = pkc(v[s]);
        }
    }
    // Stage B' (both passes; wave-local)
    const int wv = tid >> 6, jB = tid & 63;
    #pragma unroll
    for (int p = 0; p < 2; ++p){
        const int sB = wv + 8*p;
        float2 v[16];
        #pragma unroll
        for (int sp = 0; sp < 16; ++sp) v[sp] = upkc(X[sB*1024 + sp*64 + ((jB + 4*sp) & 63)]);
        twchain16<+1>(v, TWOPI_F * (float)jB / 1024.0f);
        dft16_ip<+1>(v);
        #pragma unroll
        for (int s = 0; s < 16; ++s){
            const int t = 4*(s&3) + (s>>2);
            X[sB*1024 + t*64 + ((jB + t) & 63)] = pkc(v[s]);
        }
    }
    __syncthreads();   // cross-wave: A' gathers from all chunks

    const float CSCALE = 0.1f / (16384.0f * 16384.0f);
    const float invTN2 = 1.0f / 67108.864f;   // 1/(T*N*N)
    const int lane = tid & 63, wvv = tid >> 6;   // 8 waves

    if (!is_packed){
        // ---------------- cross path (R10-verified) ----------------
        float uval[2][16];
        float lm = 0.f, lsum = 0.f;
        #pragma unroll
        for (int p = 0; p < 2; ++p){
            const int tp = tid + 512*p;
            const int baseA = L1swz(tp);
            float2 v[16];
            #pragma unroll
            for (int s = 0; s < 16; ++s) v[s] = upkc(X[s*1024 + baseA]);
            twchain16<+1>(v, TWOPI_F * (float)tp / 16384.0f);
            dft16_ip<+1>(v);
            const bool j0 = (tp == 0);
            #pragma unroll
            for (int s = 0; s < 16; ++s){
                const int t = 4*(s&3) + (s>>2);
                float uu = CSCALE * (v[s].x*v[s].x + v[s].y*v[s].y);
                uval[p][s] = uu;
                bool inv = (t == 8) && j0;
                if (!inv){ lm = fmaxf(lm, uu); lsum += uu; }
                if (t == 0 && j0) lsum += uu;
            }
        }
        __syncthreads();  // X reads done; reuse as scratch

        float* scratch = (float*)X;
        float wm = waveReduceMax(lm);
        float wsm = waveReduceSum(lsum);
        if (lane == 0){ scratch[wvv] = wm; scratch[8+wvv] = wsm; }
        __syncthreads();
        float m_b = scratch[0], sumu = scratch[8];
        #pragma unroll
        for (int i = 1; i < 8; ++i){ m_b = fmaxf(m_b, scratch[i]); sumu += scratch[8+i]; }

        float le = 0.f;
        #pragma unroll
        for (int p = 0; p < 2; ++p){
            const bool j0 = (p == 0) && (tid == 0);
            #pragma unroll
            for (int s = 0; s < 16; ++s){
                const int t = 4*(s&3) + (s>>2);
                float ex = __expf((uval[p][s] - m_b) * invTN2);
                bool inv = (t == 8) && j0;
                if (!inv) le += ((t == 0 && j0) ? 2.f : 1.f) * ex;
            }
        }
        float wle = waveReduceSum(le);
        if (lane == 0) scratch[16+wvv] = wle;
        __syncthreads();
        if (tid == 0){
            float sb2 = 0.f;
            #pragma unroll
            for (int i = 0; i < 8; ++i) sb2 += scratch[16+i];
            rec[M_WAVE + r] = make_float4(m_b, sumu, sb2, 0.f);
        }
    } else {
        // ---------------- packed-auto path ----------------
        // A' both passes; keep z bf16-packed in regs, then store lag-indexed.
        unsigned zpk[2][16];
        #pragma unroll
        for (int p = 0; p < 2; ++p){
            const int tp = tid + 512*p;
            const int baseA = L1swz(tp);
            float2 v[16];
            #pragma unroll
            for (int s = 0; s < 16; ++s) v[s] = upkc(X[s*1024 + baseA]);
            twchain16<+1>(v, TWOPI_F * (float)tp / 16384.0f);
            dft16_ip<+1>(v);
            #pragma unroll
            for (int s = 0; s < 16; ++s) zpk[p][s] = pkc(v[s]);
        }
        __syncthreads();  // all A' reads of X complete
        #pragma unroll
        for (int p = 0; p < 2; ++p){
            const int tp = tid + 512*p;
            #pragma unroll
            for (int s = 0; s < 16; ++s){
                const int t = 4*(s&3) + (s>>2);
                X[t*1024 + tp] = zpk[p][s];    // lag-indexed bf16 z
            }
        }
        __syncthreads();

        // pass 1: max & sum for both autos. Valid lags n in [N+1, 2N-1] <=> t>8 || (t==8 && tp!=0)
        float lma = 0.f, lmb = 0.f, lsa = 0.f, lsb = 0.f;
        #pragma unroll
        for (int p = 0; p < 2; ++p){
            const int tp = tid + 512*p;
            #pragma unroll
            for (int s = 0; s < 16; ++s){
                const int t = 4*(s&3) + (s>>2);
                if (t < 8) continue;
                if (t == 8 && tp == 0) continue;
                const int n = t*1024 + tp;
                float2 z  = upkc(X[n]);
                float2 zc = upkc(X[FFT_N - n]);   // n in [8193,16383] -> partner in [1,8191]
                float ar = 0.5f*(z.x + zc.x), ai = 0.5f*(z.y - zc.y);
                float br = 0.5f*(z.x - zc.x), bi = 0.5f*(z.y + zc.y);
                float ua = CSCALE*(ar*ar + ai*ai);
                float ub = CSCALE*(br*br + bi*bi);
                lma = fmaxf(lma, ua); lsa += ua;
                lmb = fmaxf(lmb, ub); lsb += ub;
            }
        }
        float wma = waveReduceMax(lma), wmb = waveReduceMax(lmb);
        float wsa = waveReduceSum(lsa), wsb = waveReduceSum(lsb);
        if (lane == 0){ scr2[wvv]=wma; scr2[8+wvv]=wmb; scr2[16+wvv]=wsa; scr2[24+wvv]=wsb; }
        __syncthreads();
        float m_a = scr2[0], m_b = scr2[8], s_a = scr2[16], s_b = scr2[24];
        #pragma unroll
        for (int i = 1; i < 8; ++i){
            m_a = fmaxf(m_a, scr2[i]);    m_b = fmaxf(m_b, scr2[8+i]);
            s_a += scr2[16+i];            s_b += scr2[24+i];
        }
        // pass 2: logsumexp partials
        float lea = 0.f, leb = 0.f;
        #pragma unroll
        for (int p = 0; p < 2; ++p){
            const int tp = tid + 512*p;
            #pragma unroll
            for (int s = 0; s < 16; ++s){
                const int t = 4*(s&3) + (s>>2);
                if (t < 8) continue;
                if (t == 8 && tp == 0) continue;
                const int n = t*1024 + tp;
                float2 z  = upkc(X[n]);
                float2 zc = upkc(X[FFT_N - n]);
                float ar = 0.5f*(z.x + zc.x), ai = 0.5f*(z.y - zc.y);
                float br = 0.5f*(z.x - zc.x), bi = 0.5f*(z.y + zc.y);
                float ua = CSCALE*(ar*ar + ai*ai);
                float ub = CSCALE*(br*br + bi*bi);
                lea += __expf((ua - m_a)*invTN2);
                leb += __expf((ub - m_b)*invTN2);
            }
        }
        float wlea = waveReduceSum(lea), wleb = waveReduceSum(leb);
        if (lane == 0){ scr2[32+wvv] = wlea; scr2[40+wvv] = wleb; }
        __syncthreads();
        if (tid == 0){
            float ta = 0.f, tb = 0.f;
            #pragma unroll
            for (int i = 0; i < 8; ++i){ ta += scr2[32+i]; tb += scr2[40+i]; }
            const int k = r - 496;
            rec[2*k]   = make_float4(m_a, s_a, ta, 0.f);
            rec[2*k+1] = make_float4(m_b, s_b, tb, 0.f);
        }
    }
}

// Merge 528 records -> 7 outputs. Single wave, shuffle-only, deterministic.
__global__ __launch_bounds__(64) void final_kernel(const float4* __restrict__ rec,
                                                   float* __restrict__ out) {
    const int lane = threadIdx.x;
    float mA = 0.f, mC = 0.f;
    for (int r = lane; r < NPAIR; r += 64){
        float mx = rec[r].x;
        if (r < M_WAVE) mA = fmaxf(mA, mx); else mC = fmaxf(mC, mx);
    }
    #pragma unroll
    for (int off = 32; off > 0; off >>= 1){
        mA = fmaxf(mA, __shfl_xor(mA, off, 64));
        mC = fmaxf(mC, __shfl_xor(mC, off, 64));
    }
    const float Mall = fmaxf(mA, mC);
    const float invTN2f = 1.0f / 67108.864f;
    double S = 0.0, sA = 0.0, sC = 0.0;
    for (int r = lane; r < NPAIR; r += 64){
        float4 rv = rec[r];
        S += (double)rv.z * (double)__expf((rv.x - Mall)*invTN2f);
        if (r < M_WAVE) sA += (double)rv.y; else sC += (double)rv.y;
    }
    #pragma unroll
    for (int off = 32; off > 0; off >>= 1){
        S  += __shfl_xor(S,  off, 64);
        sA += __shfl_xor(sA, off, 64);
        sC += __shfl_xor(sC, off, 64);
    }
    if (lane == 0){
        const double invN2 = 1.0/67108864.0;
        out[0] = (float)((double)Mall*invN2 + 1e-3*log(S));
        out[1] = (float)((double)Mall*invN2);
        out[2] = mA;
        out[3] = mC;
        out[4] = (float)((sA + sC)*invN2);
        out[5] = (float)sA;
        out[6] = (float)sC;
    }
}

extern "C" void kernel_launch(void* const* d_in, const int* in_sizes, int n_in,
                              void* d_out, int out_size, void* d_ws, size_t ws_size,
                              hipStream_t stream) {
    (void)in_sizes; (void)n_in; (void)out_size; (void)ws_size;
    const float* x = (const float*)d_in[0];
    float* out = (float*)d_out;

    unsigned* spec = (unsigned*)d_ws;   // 32*16384*4 B = 2 MiB (bf16x2)
    float4* rec = (float4*)((char*)d_ws + (size_t)M_WAVE * FFT_N * sizeof(unsigned));

    fwd_fft_kernel<<<64, 512, 0, stream>>>(x, spec);
    pair_kernel<<<512, 512, 0, stream>>>(spec, rec);
    final_kernel<<<1, 64, 0, stream>>>(rec, out);
}

// Round 12
// 47.837 us; speedup vs baseline: 1.3318x; 1.0907x over previous
//
#include <hip/hip_runtime.h>
#include <math.h>

#define M_WAVE 32
#define NLEN 8192
#define FFT_N 16384
#define NPAIR 528   // rec entries: 32 autos (rec[0..31]) + 496 cross (rec[32..527])

#define TWOPI_F 6.28318530717958647692f

__device__ __forceinline__ float2 cadd(float2 a, float2 b){return make_float2(a.x+b.x, a.y+b.y);}
__device__ __forceinline__ float2 csub(float2 a, float2 b){return make_float2(a.x-b.x, a.y-b.y);}
__device__ __forceinline__ float2 cmul(float2 a, float2 b){return make_float2(a.x*b.x-a.y*b.y, a.x*b.y+a.y*b.x);}
__device__ __forceinline__ float2 mul_i (float2 a){return make_float2(-a.y,  a.x);}
__device__ __forceinline__ float2 mul_mi(float2 a){return make_float2( a.y, -a.x);}

// bf16x2 pack/unpack: one complex float2 <-> one u32 (re=low16, im=high16)
__device__ __forceinline__ unsigned pkc(float2 v){
    unsigned r;
    asm("v_cvt_pk_bf16_f32 %0, %1, %2" : "=v"(r) : "v"(v.x), "v"(v.y));
    return r;
}
__device__ __forceinline__ float2 upkc(unsigned u){
    return make_float2(__uint_as_float(u << 16), __uint_as_float(u & 0xFFFF0000u));
}

__device__ __forceinline__ float2 dpp_xor1(float2 v){
    float2 r;
    r.x = __int_as_float(__builtin_amdgcn_mov_dpp(__float_as_int(v.x), 0xB1, 0xF, 0xF, true));
    r.y = __int_as_float(__builtin_amdgcn_mov_dpp(__float_as_int(v.y), 0xB1, 0xF, 0xF, true));
    return r;
}
__device__ __forceinline__ float2 dpp_xor2(float2 v){
    float2 r;
    r.x = __int_as_float(__builtin_amdgcn_mov_dpp(__float_as_int(v.x), 0x4E, 0xF, 0xF, true));
    r.y = __int_as_float(__builtin_amdgcn_mov_dpp(__float_as_int(v.y), 0x4E, 0xF, 0xF, true));
    return r;
}

__device__ __forceinline__ float waveReduceMax(float v) {
    #pragma unroll
    for (int off = 32; off > 0; off >>= 1) v = fmaxf(v, __shfl_down(v, off, 64));
    return v;
}
__device__ __forceinline__ float waveReduceSum(float v) {
    #pragma unroll
    for (int off = 32; off > 0; off >>= 1) v += __shfl_down(v, off, 64);
    return v;
}

// ---------- classic dft16 (natural order) ----------
template<int SGN>
__device__ __forceinline__ void dft16_tail(float2 w[16], float2 v[16]){
    const float C1 = 0.923879532511286756f;
    const float S1 = 0.382683432365089772f;
    const float R2 = 0.707106781186547524f;
    const float G = (SGN < 0) ? -1.0f : 1.0f;
    w[5]  = cmul(w[5],  make_float2( C1,  G*S1));
    w[6]  = cmul(w[6],  make_float2( R2,  G*R2));
    w[7]  = cmul(w[7],  make_float2( S1,  G*C1));
    w[9]  = cmul(w[9],  make_float2( R2,  G*R2));
    w[10] = (SGN<0) ? mul_mi(w[10]) : mul_i(w[10]);
    w[11] = cmul(w[11], make_float2(-R2,  G*R2));
    w[13] = cmul(w[13], make_float2( S1,  G*C1));
    w[14] = cmul(w[14], make_float2(-R2,  G*R2));
    w[15] = cmul(w[15], make_float2(-C1, -G*S1));
    #pragma unroll
    for (int k0 = 0; k0 < 4; ++k0){
        float2 a = w[k0*4+0], b = w[k0*4+1], c = w[k0*4+2], d = w[k0*4+3];
        float2 t0 = cadd(a,c), t1 = csub(a,c), t2 = cadd(b,d), t3 = csub(b,d);
        float2 j3 = (SGN < 0) ? mul_mi(t3) : mul_i(t3);
        v[k0]    = cadd(t0,t2);
        v[k0+4]  = cadd(t1,j3);
        v[k0+8]  = csub(t0,t2);
        v[k0+12] = csub(t1,j3);
    }
}

template<int SGN>
__device__ __forceinline__ void dft16(float2 v[16]){
    float2 w[16];
    #pragma unroll
    for (int n0 = 0; n0 < 4; ++n0){
        float2 a = v[n0], b = v[n0+4], c = v[n0+8], d = v[n0+12];
        float2 t0 = cadd(a,c), t1 = csub(a,c), t2 = cadd(b,d), t3 = csub(b,d);
        float2 j3 = (SGN < 0) ? mul_mi(t3) : mul_i(t3);
        w[n0]    = cadd(t0,t2);
        w[4+n0]  = cadd(t1,j3);
        w[8+n0]  = csub(t0,t2);
        w[12+n0] = csub(t1,j3);
    }
    dft16_tail<SGN>(w, v);
}

// forward DFT16 with inputs 8..15 == 0 (zero-padded), SGN=-1
__device__ __forceinline__ void dft16_zero8(float2 v[16]){
    float2 w[16];
    #pragma unroll
    for (int n0 = 0; n0 < 4; ++n0){
        float2 a = v[n0], b = v[n0+4];
        w[n0]    = cadd(a,b);
        w[4+n0]  = make_float2(a.x + b.y, a.y - b.x);  // a - i b
        w[8+n0]  = csub(a,b);
        w[12+n0] = make_float2(a.x - b.y, a.y + b.x);  // a + i b
    }
    dft16_tail<-1>(w, v);
}

// ---------- in-place dft16, digit-reversed output: slot s holds y[4*(s&3)+(s>>2)].
template<int SGN>
__device__ __forceinline__ void dft16_ip(float2 v[16]){
    const float C1 = 0.923879532511286756f;
    const float S1 = 0.382683432365089772f;
    const float R2 = 0.707106781186547524f;
    const float G = (SGN < 0) ? -1.0f : 1.0f;
    #pragma unroll
    for (int n1 = 0; n1 < 4; ++n1){
        float2 a = v[n1], b = v[n1+4], c = v[n1+8], d = v[n1+12];
        float2 t0 = cadd(a,c), t1 = csub(a,c), t2 = cadd(b,d), t3 = csub(b,d);
        float2 j3 = (SGN < 0) ? mul_mi(t3) : mul_i(t3);
        v[n1]    = cadd(t0,t2);
        v[n1+4]  = cadd(t1,j3);
        v[n1+8]  = csub(t0,t2);
        v[n1+12] = csub(t1,j3);
    }
    v[5]  = cmul(v[5],  make_float2( C1,  G*S1));
    v[6]  = cmul(v[6],  make_float2( R2,  G*R2));
    v[7]  = cmul(v[7],  make_float2( S1,  G*C1));
    v[9]  = cmul(v[9],  make_float2( R2,  G*R2));
    v[10] = (SGN<0) ? mul_mi(v[10]) : mul_i(v[10]);
    v[11] = cmul(v[11], make_float2(-R2,  G*R2));
    v[13] = cmul(v[13], make_float2( S1,  G*C1));
    v[14] = cmul(v[14], make_float2(-R2,  G*R2));
    v[15] = cmul(v[15], make_float2(-C1, -G*S1));
    #pragma unroll
    for (int kl = 0; kl < 4; ++kl){
        float2 a = v[4*kl], b = v[4*kl+1], c = v[4*kl+2], d = v[4*kl+3];
        float2 t0 = cadd(a,c), t1 = csub(a,c), t2 = cadd(b,d), t3 = csub(b,d);
        float2 j3 = (SGN < 0) ? mul_mi(t3) : mul_i(t3);
        v[4*kl]   = cadd(t0,t2);
        v[4*kl+1] = cadd(t1,j3);
        v[4*kl+2] = csub(t0,t2);
        v[4*kl+3] = csub(t1,j3);
    }
}

template<int SGN>
__device__ __forceinline__ void twchain16(float2 v[16], float theta){
    float th = (SGN < 0) ? -theta : theta;
    float s1,c1; __sincosf(th, &s1, &c1);
    float s4,c4; __sincosf(4.0f*th, &s4, &c4);
    float2 w1 = make_float2(c1,s1), w4 = make_float2(c4,s4);
    float2 lo2 = cmul(w1,w1), lo3 = cmul(lo2,w1);
    float2 hi2 = cmul(w4,w4), hi3 = cmul(hi2,w4);
    float2 lo[4] = {make_float2(1.f,0.f), w1, lo2, lo3};
    float2 hi[4] = {make_float2(1.f,0.f), w4, hi2, hi3};
    #pragma unroll
    for (int s = 1; s < 16; ++s){
        v[s] = cmul(v[s], cmul(hi[s>>2], lo[s&3]));
    }
}

__device__ __forceinline__ int L1swz(int e){
    return (e & ~63) | (((e & 63) + ((e >> 6) & 15)) & 63);
}

// F1 (stage A): 128 blocks = 32 m x 4 col-groups, 256 threads, 1 column/thread,
// zero redundancy. Writes 16 twiddled chunk outputs to bf16 mid in the L1swz
// layout stage B expects (byte-identical addressing to the verified LDS path).
__global__ __launch_bounds__(256, 1) void stageA_kernel(const float* __restrict__ x,
                                                        unsigned* __restrict__ mid) {
    const int bx = blockIdx.x, m = bx >> 2, grp = bx & 3;
    const int j = grp*256 + threadIdx.x;      // column 0..1023
    float2 v[16];
    #pragma unroll
    for (int s = 0; s < 8; ++s){
        float ph = TWOPI_F * x[m*NLEN + s*1024 + j];
        float sn,cs; __sincosf(ph,&sn,&cs);
        v[s] = make_float2(cs,sn);
    }
    dft16_zero8(v);
    twchain16<-1>(v, TWOPI_F * (float)j / 16384.0f);  // v[s] *= e^{-i 2pi j s / 16384}
    unsigned* dst = mid + (size_t)m*FFT_N + L1swz(j);
    #pragma unroll
    for (int s = 0; s < 16; ++s) dst[s*1024] = pkc(v[s]);
}

// F2 (stages B+C): 128 blocks = 32 m x 4 chunk-groups, 256 threads (4 waves,
// wave wv = chunk 4*g+wv). Coalesced mid reads, wave-local LDS, no barriers.
// Index math verbatim from the verified fwd body (8*hf+wv -> ch).
__global__ __launch_bounds__(256, 1) void bc_kernel(const unsigned* __restrict__ mid,
                                                    unsigned* __restrict__ spec) {
    __shared__ float2 X[4096];  // 32 KiB, 4 waves x 1024
    const int bx = blockIdx.x, m = bx >> 2, g = bx & 3;
    const int tid = threadIdx.x;
    const int wv = tid >> 6, jB = tid & 63;
    const int ch = g*4 + wv;
    const unsigned* base = mid + (size_t)m*FFT_N + ch*1024;
    float2 v[16];

    // Stage B
    #pragma unroll
    for (int t = 0; t < 16; ++t) v[t] = upkc(base[t*64 + ((jB + t) & 63)]);
    dft16<-1>(v);
    twchain16<-1>(v, TWOPI_F * (float)jB / 1024.0f);
    #pragma unroll
    for (int sp = 0; sp < 16; ++sp) X[wv*1024 + sp*64 + ((jB + 4*sp) & 63)] = v[sp];
    // no barrier: stage C reads only this wave's region

    // Stage C
    {
        const int bl = (tid & 63) >> 2, jC = tid & 3;
        #pragma unroll
        for (int a = 0; a < 16; ++a)
            v[a] = X[wv*1024 + bl*64 + ((4*a + jC + 4*bl) & 63)];
        dft16<-1>(v);
        twchain16<-1>(v, TWOPI_F * (float)jC / 64.0f);
        const bool odd1 = (jC & 1) != 0;
        const bool odd2 = (jC & 2) != 0;
        #pragma unroll
        for (int e = 0; e < 16; ++e){
            float2 p = dpp_xor2(v[e]);
            float2 t = odd2 ? csub(p, v[e]) : cadd(v[e], p);
            float2 q = dpp_xor1(t);
            float2 re = odd1 ? csub(q, t) : cadd(t, q);
            float2 ro = odd1 ? cadd(q, mul_i(t)) : cadd(t, mul_mi(q));
            v[e] = odd2 ? ro : re;
        }
        const int u = ((jC & 1) << 1) | (jC >> 1);
        uint4* dst = (uint4*)(spec + (size_t)m*FFT_N + ch*1024 + bl*64 + u*16);
        #pragma unroll
        for (int e = 0; e < 4; ++e)
            dst[e] = make_uint4(pkc(v[4*e]), pkc(v[4*e+1]), pkc(v[4*e+2]), pkc(v[4*e+3]));
    }
}

// Pair kernel: 512 blocks (R11-verified, unchanged).
__global__ __launch_bounds__(512, 4) void pair_kernel(const unsigned* __restrict__ spec,
                                                      float4* __restrict__ rec) {
    __shared__ unsigned X[FFT_N];  // 64 KiB, bf16x2 per element
    __shared__ float scr2[64];
    const int r = blockIdx.x, tid = threadIdx.x;
    const bool is_packed = (r >= 496);
    int a, b;
    if (is_packed){
        const int k = r - 496; a = 2*k; b = 2*k + 1;
    } else {
        int t = r; a = 0; int rem = M_WAVE - 1;
        while (t >= rem){ t -= rem; ++a; rem = M_WAVE - 1 - a; }
        b = a + 1 + t;
    }
    const int jC = tid & 3;
    const int u = ((jC & 1) << 1) | (jC >> 1);
    const bool odd1 = (jC & 1) != 0;
    const bool odd2 = (jC & 2) != 0;

    // Stage C' (both passes): load, adjoint lane-DFT4, tw, dft16_ip, store
    #pragma unroll
    for (int p = 0; p < 2; ++p){
        const int blk = (tid >> 2) + 128*p;   // [0,256)
        float2 v[16];
        const uint4* pa = (const uint4*)(spec + (size_t)a*FFT_N + blk*64 + u*16);
        const uint4* pb = (const uint4*)(spec + (size_t)b*FFT_N + blk*64 + u*16);
        #pragma unroll
        for (int e = 0; e < 4; ++e){
            uint4 A = pa[e], B = pb[e];
            float2 a0 = upkc(A.x), a1 = upkc(A.y), a2 = upkc(A.z), a3 = upkc(A.w);
            float2 b0 = upkc(B.x), b1 = upkc(B.y), b2 = upkc(B.z), b3 = upkc(B.w);
            if (is_packed){
                v[4*e+0] = make_float2(a0.x*a0.x + a0.y*a0.y, b0.x*b0.x + b0.y*b0.y);
                v[4*e+1] = make_float2(a1.x*a1.x + a1.y*a1.y, b1.x*b1.x + b1.y*b1.y);
                v[4*e+2] = make_float2(a2.x*a2.x + a2.y*a2.y, b2.x*b2.x + b2.y*b2.y);
                v[4*e+3] = make_float2(a3.x*a3.x + a3.y*a3.y, b3.x*b3.x + b3.y*b3.y);
            } else {
                v[4*e+0] = make_float2(b0.x*a0.x + b0.y*a0.y, b0.y*a0.x - b0.x*a0.y);
                v[4*e+1] = make_float2(b1.x*a1.x + b1.y*a1.y, b1.y*a1.x - b1.x*a1.y);
                v[4*e+2] = make_float2(b2.x*a2.x + b2.y*a2.y, b2.y*a2.x - b2.x*a2.y);
                v[4*e+3] = make_float2(b3.x*a3.x + b3.y*a3.y, b3.y*a3.x - b3.x*a3.y);
            }
        }
        #pragma unroll
        for (int e = 0; e < 16; ++e){
            float2 q = dpp_xor1(v[e]);
            float2 t = odd1 ? csub(q, v[e]) : cadd(v[e], q);
            float2 pp = dpp_xor2(t);
            float2 re = odd2 ? csub(pp, t) : cadd(t, pp);
            float2 ro = odd2 ? csub(pp, mul_i(t)) : cadd(t, mul_i(pp));
            v[e] = odd1 ? ro : re;
        }
        twchain16<+1>(v, TWOPI_F * (float)jC / 64.0f);
        dft16_ip<+1>(v);
        const int rot = 4*(blk & 15);
        #pragma unroll
        for (int s = 0; s < 16; ++s){
            const int t = 4*(s&3) + (s>>2);   // digit held in slot s
            X[blk*64 + ((4*t + jC + rot) & 63)] = pkc(v[s]);
        }
    }
    // Stage B' (both passes; wave-local)
    const int wv = tid >> 6, jB = tid & 63;
    #pragma unroll
    for (int p = 0; p < 2; ++p){
        const int sB = wv + 8*p;
        float2 v[16];
        #pragma unroll
        for (int sp = 0; sp < 16; ++sp) v[sp] = upkc(X[sB*1024 + sp*64 + ((jB + 4*sp) & 63)]);
        twchain16<+1>(v, TWOPI_F * (float)jB / 1024.0f);
        dft16_ip<+1>(v);
        #pragma unroll
        for (int s = 0; s < 16; ++s){
            const int t = 4*(s&3) + (s>>2);
            X[sB*1024 + t*64 + ((jB + t) & 63)] = pkc(v[s]);
        }
    }
    __syncthreads();   // cross-wave: A' gathers from all chunks

    const float CSCALE = 0.1f / (16384.0f * 16384.0f);
    const float invTN2 = 1.0f / 67108.864f;   // 1/(T*N*N)
    const int lane = tid & 63, wvv = tid >> 6;   // 8 waves

    if (!is_packed){
        float uval[2][16];
        float lm = 0.f, lsum = 0.f;
        #pragma unroll
        for (int p = 0; p < 2; ++p){
            const int tp = tid + 512*p;
            const int baseA = L1swz(tp);
            float2 v[16];
            #pragma unroll
            for (int s = 0; s < 16; ++s) v[s] = upkc(X[s*1024 + baseA]);
            twchain16<+1>(v, TWOPI_F * (float)tp / 16384.0f);
            dft16_ip<+1>(v);
            const bool j0 = (tp == 0);
            #pragma unroll
            for (int s = 0; s < 16; ++s){
                const int t = 4*(s&3) + (s>>2);
                float uu = CSCALE * (v[s].x*v[s].x + v[s].y*v[s].y);
                uval[p][s] = uu;
                bool inv = (t == 8) && j0;
                if (!inv){ lm = fmaxf(lm, uu); lsum += uu; }
                if (t == 0 && j0) lsum += uu;
            }
        }
        __syncthreads();  // X reads done; reuse as scratch

        float* scratch = (float*)X;
        float wm = waveReduceMax(lm);
        float wsm = waveReduceSum(lsum);
        if (lane == 0){ scratch[wvv] = wm; scratch[8+wvv] = wsm; }
        __syncthreads();
        float m_b = scratch[0], sumu = scratch[8];
        #pragma unroll
        for (int i = 1; i < 8; ++i){ m_b = fmaxf(m_b, scratch[i]); sumu += scratch[8+i]; }

        float le = 0.f;
        #pragma unroll
        for (int p = 0; p < 2; ++p){
            const bool j0 = (p == 0) && (tid == 0);
            #pragma unroll
            for (int s = 0; s < 16; ++s){
                const int t = 4*(s&3) + (s>>2);
                float ex = __expf((uval[p][s] - m_b) * invTN2);
                bool inv = (t == 8) && j0;
                if (!inv) le += ((t == 0 && j0) ? 2.f : 1.f) * ex;
            }
        }
        float wle = waveReduceSum(le);
        if (lane == 0) scratch[16+wvv] = wle;
        __syncthreads();
        if (tid == 0){
            float sb2 = 0.f;
            #pragma unroll
            for (int i = 0; i < 8; ++i) sb2 += scratch[16+i];
            rec[M_WAVE + r] = make_float4(m_b, sumu, sb2, 0.f);
        }
    } else {
        unsigned zpk[2][16];
        #pragma unroll
        for (int p = 0; p < 2; ++p){
            const int tp = tid + 512*p;
            const int baseA = L1swz(tp);
            float2 v[16];
            #pragma unroll
            for (int s = 0; s < 16; ++s) v[s] = upkc(X[s*1024 + baseA]);
            twchain16<+1>(v, TWOPI_F * (float)tp / 16384.0f);
            dft16_ip<+1>(v);
            #pragma unroll
            for (int s = 0; s < 16; ++s) zpk[p][s] = pkc(v[s]);
        }
        __syncthreads();  // all A' reads of X complete
        #pragma unroll
        for (int p = 0; p < 2; ++p){
            const int tp = tid + 512*p;
            #pragma unroll
            for (int s = 0; s < 16; ++s){
                const int t = 4*(s&3) + (s>>2);
                X[t*1024 + tp] = zpk[p][s];    // lag-indexed bf16 z
            }
        }
        __syncthreads();

        float lma = 0.f, lmb = 0.f, lsa = 0.f, lsb = 0.f;
        #pragma unroll
        for (int p = 0; p < 2; ++p){
            const int tp = tid + 512*p;
            #pragma unroll
            for (int s = 0; s < 16; ++s){
                const int t = 4*(s&3) + (s>>2);
                if (t < 8) continue;
                if (t == 8 && tp == 0) continue;
                const int n = t*1024 + tp;
                float2 z  = upkc(X[n]);
                float2 zc = upkc(X[FFT_N - n]);
                float ar = 0.5f*(z.x + zc.x), ai = 0.5f*(z.y - zc.y);
                float br = 0.5f*(z.x - zc.x), bi = 0.5f*(z.y + zc.y);
                float ua = CSCALE*(ar*ar + ai*ai);
                float ub = CSCALE*(br*br + bi*bi);
                lma = fmaxf(lma, ua); lsa += ua;
                lmb = fmaxf(lmb, ub); lsb += ub;
            }
        }
        float wma = waveReduceMax(lma), wmb = waveReduceMax(lmb);
        float wsa = waveReduceSum(lsa), wsb = waveReduceSum(lsb);
        if (lane == 0){ scr2[wvv]=wma; scr2[8+wvv]=wmb; scr2[16+wvv]=wsa; scr2[24+wvv]=wsb; }
        __syncthreads();
        float m_a = scr2[0], m_b = scr2[8], s_a = scr2[16], s_b = scr2[24];
        #pragma unroll
        for (int i = 1; i < 8; ++i){
            m_a = fmaxf(m_a, scr2[i]);    m_b = fmaxf(m_b, scr2[8+i]);
            s_a += scr2[16+i];            s_b += scr2[24+i];
        }
        float lea = 0.f, leb = 0.f;
        #pragma unroll
        for (int p = 0; p < 2; ++p){
            const int tp = tid + 512*p;
            #pragma unroll
            for (int s = 0; s < 16; ++s){
                const int t = 4*(s&3) + (s>>2);
                if (t < 8) continue;
                if (t == 8 && tp == 0) continue;
                const int n = t*1024 + tp;
                float2 z  = upkc(X[n]);
                float2 zc = upkc(X[FFT_N - n]);
                float ar = 0.5f*(z.x + zc.x), ai = 0.5f*(z.y - zc.y);
                float br = 0.5f*(z.x - zc.x), bi = 0.5f*(z.y + zc.y);
                float ua = CSCALE*(ar*ar + ai*ai);
                float ub = CSCALE*(br*br + bi*bi);
                lea += __expf((ua - m_a)*invTN2);
                leb += __expf((ub - m_b)*invTN2);
            }
        }
        float wlea = waveReduceSum(lea), wleb = waveReduceSum(leb);
        if (lane == 0){ scr2[32+wvv] = wlea; scr2[40+wvv] = wleb; }
        __syncthreads();
        if (tid == 0){
            float ta = 0.f, tb = 0.f;
            #pragma unroll
            for (int i = 0; i < 8; ++i){ ta += scr2[32+i]; tb += scr2[40+i]; }
            const int k = r - 496;
            rec[2*k]   = make_float4(m_a, s_a, ta, 0.f);
            rec[2*k+1] = make_float4(m_b, s_b, tb, 0.f);
        }
    }
}

// Merge 528 records -> 7 outputs. Single wave, shuffle-only, deterministic.
__global__ __launch_bounds__(64) void final_kernel(const float4* __restrict__ rec,
                                                   float* __restrict__ out) {
    const int lane = threadIdx.x;
    float mA = 0.f, mC = 0.f;
    for (int r = lane; r < NPAIR; r += 64){
        float mx = rec[r].x;
        if (r < M_WAVE) mA = fmaxf(mA, mx); else mC = fmaxf(mC, mx);
    }
    #pragma unroll
    for (int off = 32; off > 0; off >>= 1){
        mA = fmaxf(mA, __shfl_xor(mA, off, 64));
        mC = fmaxf(mC, __shfl_xor(mC, off, 64));
    }
    const float Mall = fmaxf(mA, mC);
    const float invTN2f = 1.0f / 67108.864f;
    double S = 0.0, sA = 0.0, sC = 0.0;
    for (int r = lane; r < NPAIR; r += 64){
        float4 rv = rec[r];
        S += (double)rv.z * (double)__expf((rv.x - Mall)*invTN2f);
        if (r < M_WAVE) sA += (double)rv.y; else sC += (double)rv.y;
    }
    #pragma unroll
    for (int off = 32; off > 0; off >>= 1){
        S  += __shfl_xor(S,  off, 64);
        sA += __shfl_xor(sA, off, 64);
        sC += __shfl_xor(sC, off, 64);
    }
    if (lane == 0){
        const double invN2 = 1.0/67108864.0;
        out[0] = (float)((double)Mall*invN2 + 1e-3*log(S));
        out[1] = (float)((double)Mall*invN2);
        out[2] = mA;
        out[3] = mC;
        out[4] = (float)((sA + sC)*invN2);
        out[5] = (float)sA;
        out[6] = (float)sC;
    }
}

extern "C" void kernel_launch(void* const* d_in, const int* in_sizes, int n_in,
                              void* d_out, int out_size, void* d_ws, size_t ws_size,
                              hipStream_t stream) {
    (void)in_sizes; (void)n_in; (void)out_size; (void)ws_size;
    const float* x = (const float*)d_in[0];
    float* out = (float*)d_out;

    unsigned* spec = (unsigned*)d_ws;                                   // 2 MiB
    float4* rec = (float4*)((char*)d_ws + (size_t)M_WAVE * FFT_N * 4);  // 8448 B
    unsigned* mid = (unsigned*)((char*)d_ws + (size_t)M_WAVE * FFT_N * 4
                                + (size_t)NPAIR * sizeof(float4));      // 2 MiB

    stageA_kernel<<<128, 256, 0, stream>>>(x, mid);
    bc_kernel<<<128, 256, 0, stream>>>(mid, spec);
    pair_kernel<<<512, 512, 0, stream>>>(spec, rec);
    final_kernel<<<1, 64, 0, stream>>>(rec, out);
}